// Round 2
// baseline (1362.428 us; speedup 1.0000x reference)
//
#include <hip/hip_runtime.h>
#include <math.h>

#define BB 4
#define CC 64
#define NN 8192
#define OO 128
#define KK 20
#define DD 128            // 2*CC
#define BUFSZ 25          // per-lane append buffer (25*8B=200B lane stride -> spread banks)

typedef short bf16x8 __attribute__((ext_vector_type(8)));   // 8 bf16 (4 VGPR)
typedef float f32x4 __attribute__((ext_vector_type(4)));
typedef unsigned short u16x8 __attribute__((ext_vector_type(8)));
typedef unsigned long long u64;

typedef __attribute__((address_space(1))) const void gvoid;
typedef __attribute__((address_space(3))) void lvoid;

// orderable-key packing: (float value, candidate idx) -> u64, so that
// u64-descending == (value desc, idx asc). Matches jax.lax.top_k tie-breaking.
__device__ __forceinline__ u64 packkey(float v, int idx) {
  unsigned u = __float_as_uint(v);
  unsigned o = ((int)u < 0) ? ~u : (u | 0x80000000u);
  return (((u64)o) << 32) | (unsigned)(~idx);
}
__device__ __forceinline__ float keyval(u64 k) {
  unsigned o = (unsigned)(k >> 32);
  unsigned u = (o & 0x80000000u) ? (o ^ 0x80000000u) : ~o;
  return __uint_as_float(u);
}
#define INITKEY (((u64)0x007FFFFFu) << 32)   // packkey(-inf, 0xFFFFFFFF)

__device__ __forceinline__ unsigned short bf_rne(float f) {
  unsigned u = __float_as_uint(f);
  u += 0x7FFFu + ((u >> 16) & 1u);
  return (unsigned short)(u >> 16);
}
__device__ __forceinline__ float bf_f(unsigned short h) {
  return __uint_as_float(((unsigned)h) << 16);
}

// ---------------------------------------------------------------------------
// prep: xt[b][n][c] (fp32, for d1), xx[b][n], and xs[b][n][192] = 3-way bf16
// split [h(64)|m(64)|l(64)] stored PRE-SWIZZLED: the 16B-group at logical
// byte offset o lands at o ^ ((n&7)<<4) (XOR of bits 4-6, stays inside the
// row's 128B thirds). Linear global_load_lds of a 64-row tile then yields a
// bank-uniform LDS layout for the MFMA A-fragment ds_read_b128 pattern.
// ---------------------------------------------------------------------------
__global__ __launch_bounds__(128) void prep_kernel(const float* __restrict__ x,
                                                   float* __restrict__ xt,
                                                   float* __restrict__ xx,
                                                   unsigned short* __restrict__ xs) {
  __shared__ float tile[128][CC + 1];
  const int tid = threadIdx.x;
  const int b = blockIdx.y;
  const int n0 = blockIdx.x * 128;
  const float* xb = x + (size_t)b * CC * NN;
  float acc = 0.0f;
  #pragma unroll 8
  for (int c = 0; c < CC; ++c) {
    float v = xb[(size_t)c * NN + n0 + tid];   // coalesced over tid
    acc += v * v;
    tile[tid][c] = v;
  }
  xx[b * NN + n0 + tid] = acc;

  // 3-way bf16 split, swizzled 16B-group stores (thread owns its own row)
  {
    const int n = n0 + tid;
    char* xsrow = ((char*)xs) + ((size_t)b * NN + n) * 384;
    const int swn = (n & 7) << 4;
    #pragma unroll
    for (int gr = 0; gr < 8; ++gr) {
      u16x8 h8, m8, l8;
      #pragma unroll
      for (int e = 0; e < 8; ++e) {
        float v = tile[tid][gr * 8 + e];
        unsigned short h = bf_rne(v);
        float r = v - bf_f(h);
        unsigned short m = bf_rne(r);
        r -= bf_f(m);
        unsigned short l = bf_rne(r);
        h8[e] = (unsigned short)h; m8[e] = m; l8[e] = l;
      }
      *(u16x8*)(xsrow + (((gr * 16) + 0) ^ swn)) = h8;
      *(u16x8*)(xsrow + (((gr * 16) + 128) ^ swn)) = m8;
      *(u16x8*)(xsrow + (((gr * 16) + 256) ^ swn)) = l8;
    }
  }

  __syncthreads();
  float* xtb = xt + ((size_t)b * NN + n0) * CC;
  #pragma unroll 8
  for (int t = tid; t < 128 * CC; t += 128) {  // coalesced row writes
    xtb[t] = tile[t >> 6][t & 63];
  }
}

// ---------------------------------------------------------------------------
// knn: MFMA distance matrix + per-lane buffered top-20.
// Block = 4 waves, 64 queries (wave w owns 16). Candidate tiles of 64 staged
// via global_load_lds (24 KB, pre-swizzled rows). Per wave, per tile: 4
// subtiles x 18 mfma_f32_16x16x32_bf16 (3-way bf16 split, all 9 cross terms,
// small-magnitude products accumulated first -> fp32-grade dot error).
// D layout (m89): query = lane&15, candidate = ct*16 + (lane>>4)*4 + j, so
// each lane owns ONE query and a fixed 16-of-64 residue class of candidates;
// the union of per-class top-20s covers the true top-20. Passing values are
// appended (predicated ds_write of one packed u64 key, ~6 instr) to a
// per-lane LDS buffer; rare rebuilds fold the buffer into a register-sorted
// top-20 and tighten the threshold. Epilogue: 4-way in-LDS merge writes fidx
// directly (no separate merge kernel, no pval/pidx arrays).
// ---------------------------------------------------------------------------
__global__ __launch_bounds__(256, 2) void knn_kernel(
    const unsigned short* __restrict__ xs, const float* __restrict__ xx,
    int* __restrict__ fidx) {
  __shared__ unsigned short atile[64 * 192];   // 24576 B, swizzled rows
  __shared__ float cxx[64];
  __shared__ u64 abuf[4][64][BUFSZ];           // 51200 B  (total LDS 76032 B)

  const int tid = threadIdx.x;
  const int w = tid >> 6;
  const int lane = tid & 63;
  const int r = lane & 15;    // query col (B) / cand row (A) within subtile
  const int g = lane >> 4;    // k-group
  const int b = blockIdx.y;
  const int qbase = blockIdx.x * 64 + w * 16;
  const int q = qbase + r;
  const char* xsb = ((const char*)xs) + (size_t)b * NN * 384;

  // query B-frags: bq[split][k-chunk]; lane holds k = (lane>>4)*8+[0..8) of 32
  bf16x8 bq[3][2];
  {
    const char* qrow = xsb + (size_t)q * 384;
    const int sw = (q & 7) << 4;
    #pragma unroll
    for (int s = 0; s < 3; ++s)
      #pragma unroll
      for (int c = 0; c < 2; ++c)
        bq[s][c] = *(const bf16x8*)(qrow + ((s * 128 + c * 64 + g * 16) ^ sw));
  }
  const float xxq = xx[b * NN + q];

  u64 tk[KK];
  #pragma unroll
  for (int j = 0; j < KK; ++j) tk[j] = INITKEY;
  float minv = -INFINITY;
  int cnt = 0;
  u64* mybuf = &abuf[w][lane][0];

  for (int t = 0; t < NN / 64; ++t) {
    // --- stage candidate tile (linear copy of pre-swizzled rows) ---
    {
      const char* src = xsb + (size_t)t * 64 * 384;
      #pragma unroll
      for (int it = 0; it < 6; ++it) {
        __builtin_amdgcn_global_load_lds(
            (gvoid*)(src + it * 4096 + tid * 16),
            (lvoid*)(((char*)atile) + it * 4096 + tid * 16), 16, 0, 0);
      }
      if (tid < 16) {
        __builtin_amdgcn_global_load_lds(
            (gvoid*)(xx + b * NN + t * 64 + tid * 4),
            (lvoid*)(cxx + tid * 4), 16, 0, 0);
      }
    }
    __syncthreads();   // drains vmcnt (compiler emits full waitcnt pre-barrier)

    // --- compute 4 subtiles of 16 candidates each ---
    #pragma unroll
    for (int ct = 0; ct < 4; ++ct) {
      const char* arow = ((const char*)atile) + (ct * 16 + r) * 384;
      const int sw = (r & 7) << 4;
      bf16x8 a6[6];
      #pragma unroll
      for (int c6 = 0; c6 < 6; ++c6)
        a6[c6] = *(const bf16x8*)(arow + ((c6 * 64 + g * 16) ^ sw));
      f32x4 acc = {0.f, 0.f, 0.f, 0.f};
      #pragma unroll
      for (int s = 2; s >= 0; --s)  // b-split l,m first: small terms accumulate first
        #pragma unroll
        for (int c6 = 0; c6 < 6; ++c6)
          acc = __builtin_amdgcn_mfma_f32_16x16x32_bf16(a6[c6], bq[s][c6 & 1],
                                                        acc, 0, 0, 0);
      #pragma unroll
      for (int j = 0; j < 4; ++j) {
        const int ml = ct * 16 + g * 4 + j;
        float pd = (-xxq - (-2.0f * acc[j])) - cxx[ml];  // reference expr shape
        if (pd > minv) { mybuf[cnt] = packkey(pd, t * 64 + ml); ++cnt; }
      }
    }
    __syncthreads();   // atile consumed; next stage may overwrite

    // --- rebuild threshold when any lane's buffer is getting full ---
    // invariant: cnt <= 9 at tile start, <= 16 appends/tile -> cnt <= 25 = BUFSZ
    if (__any(cnt > BUFSZ - 16)) {
      int mxc = cnt;
      #pragma unroll
      for (int o = 32; o > 0; o >>= 1) {
        int v = __shfl_xor(mxc, o);
        mxc = mxc > v ? mxc : v;
      }
      for (int i = 0; i < mxc; ++i) {
        u64 k = (i < cnt) ? mybuf[i] : 0ULL;
        if (k > tk[KK - 1]) {
          #pragma unroll
          for (int jj = KK - 1; jj >= 1; --jj)
            tk[jj] = (k > tk[jj - 1]) ? tk[jj - 1] : ((k > tk[jj]) ? k : tk[jj]);
          tk[0] = (k > tk[0]) ? k : tk[0];
        }
      }
      cnt = 0;
      minv = keyval(tk[KK - 1]);
    }
  }

  // --- flush remaining buffered candidates ---
  {
    int mxc = cnt;
    #pragma unroll
    for (int o = 32; o > 0; o >>= 1) {
      int v = __shfl_xor(mxc, o);
      mxc = mxc > v ? mxc : v;
    }
    for (int i = 0; i < mxc; ++i) {
      u64 k = (i < cnt) ? mybuf[i] : 0ULL;
      if (k > tk[KK - 1]) {
        #pragma unroll
        for (int jj = KK - 1; jj >= 1; --jj)
          tk[jj] = (k > tk[jj - 1]) ? tk[jj - 1] : ((k > tk[jj]) ? k : tk[jj]);
        tk[0] = (k > tk[0]) ? k : tk[0];
      }
    }
  }

  // --- epilogue: 4-way merge of the per-lane class lists -> fidx ---
  u64* ml = &abuf[w][0][0];   // reuse buffer space: 64 lanes x 20 keys
  #pragma unroll
  for (int j = 0; j < KK; ++j) ml[lane * KK + j] = tk[j];
  __syncthreads();
  if (lane < 16) {
    int* fo = fidx + ((size_t)b * NN + qbase + lane) * KK;
    const u64* L0 = ml + (lane + 0) * KK;
    const u64* L1 = ml + (lane + 16) * KK;
    const u64* L2 = ml + (lane + 32) * KK;
    const u64* L3 = ml + (lane + 48) * KK;
    int p0 = 0, p1 = 0, p2 = 0, p3 = 0;
    u64 h0 = L0[0], h1 = L1[0], h2 = L2[0], h3 = L3[0];
    #pragma unroll
    for (int k = 0; k < KK; ++k) {
      u64 bv = h0; int bc = 0;
      if (h1 > bv) { bv = h1; bc = 1; }
      if (h2 > bv) { bv = h2; bc = 2; }
      if (h3 > bv) { bv = h3; bc = 3; }
      fo[k] = (int)(~(unsigned)bv);
      if (bc == 0)      { ++p0; h0 = (p0 < KK) ? L0[p0] : 0ULL; }
      else if (bc == 1) { ++p1; h1 = (p1 < KK) ? L1[p1] : 0ULL; }
      else if (bc == 2) { ++p2; h2 = (p2 < KK) ? L2[p2] : 0ULL; }
      else              { ++p3; h3 = (p3 < KK) ? L3[p3] : 0ULL; }
    }
  }
}

// ---------------------------------------------------------------------------
// d1: per n compute h[k][d] = y_k . W1a_d + t_d, softmax over k per d, then
// g[d] = sum_k feats[k][d]*gate[k][d]. (unchanged from verified baseline)
// ---------------------------------------------------------------------------
__global__ __launch_bounds__(256) void d1_kernel(const float* __restrict__ xt,
                                                 const float* __restrict__ W1,
                                                 const int* __restrict__ fidx,
                                                 float* __restrict__ gbuf) {
  __shared__ float w1t[DD * DD];  // [c][d] swizzled: addr = c*128 + (d ^ (c&31))
  const int tid = threadIdx.x;
  const int b = blockIdx.y;
  const int n0 = blockIdx.x * 32;
  for (int t = tid; t < DD * DD; t += 256) {
    int dd = t >> 7, c = t & 127;
    w1t[c * DD + (dd ^ (c & 31))] = W1[t];
  }
  __syncthreads();
  const int half = tid >> 7;
  const int d = tid & 127;
  const float* xtb = xt + (size_t)b * NN * CC;

  for (int i = 0; i < 16; ++i) {
    const int n = n0 + half + 2 * i;
    const int* kp = fidx + ((size_t)b * NN + n) * KK;
    int ki[KK];
    #pragma unroll
    for (int k = 0; k < KK; ++k) ki[k] = kp[k];

    float h[KK];
    #pragma unroll
    for (int k = 0; k < KK; ++k) h[k] = 0.0f;
    float td = 0.0f;
    const float4* zp = (const float4*)(xtb + (size_t)n * CC);
    for (int c4 = 0; c4 < 16; ++c4) {
      const int c = c4 * 4;
      float4 z4 = zp[c4];
      float wa0 = w1t[(c + 0) * DD + (d ^ ((c + 0) & 31))];
      float wa1 = w1t[(c + 1) * DD + (d ^ ((c + 1) & 31))];
      float wa2 = w1t[(c + 2) * DD + (d ^ ((c + 2) & 31))];
      float wa3 = w1t[(c + 3) * DD + (d ^ ((c + 3) & 31))];
      float wb0 = w1t[(c + 64) * DD + (d ^ ((c + 64) & 31))];
      float wb1 = w1t[(c + 65) * DD + (d ^ ((c + 65) & 31))];
      float wb2 = w1t[(c + 66) * DD + (d ^ ((c + 66) & 31))];
      float wb3 = w1t[(c + 67) * DD + (d ^ ((c + 67) & 31))];
      td += z4.x * (wb0 - wa0) + z4.y * (wb1 - wa1) + z4.z * (wb2 - wa2) + z4.w * (wb3 - wa3);
      #pragma unroll
      for (int k = 0; k < KK; ++k) {
        float4 y4 = *(const float4*)(xtb + (size_t)ki[k] * CC + c);
        h[k] += y4.x * wa0 + y4.y * wa1 + y4.z * wa2 + y4.w * wa3;
      }
    }
    float m = h[0] + td;
    #pragma unroll
    for (int k = 0; k < KK; ++k) { h[k] += td; m = fmaxf(m, h[k]); }
    float e[KK];
    float s = 0.0f;
    #pragma unroll
    for (int k = 0; k < KK; ++k) { e[k] = expf(h[k] - m); s += e[k]; }
    const float inv = 1.0f / s;

    float g;
    if (d < 64) {  // wave-uniform branch
      const float zd = xtb[(size_t)n * CC + d];
      g = 0.0f;
      #pragma unroll
      for (int k = 0; k < KK; ++k) {
        const float yk = xtb[(size_t)ki[k] * CC + d];
        g += (yk - zd) * (e[k] * inv);
      }
    } else {
      const float zd = xtb[(size_t)n * CC + (d - 64)];
      float sg = 0.0f;
      #pragma unroll
      for (int k = 0; k < KK; ++k) sg += e[k] * inv;
      g = zd * sg;
    }
    gbuf[((size_t)b * NN + n) * DD + d] = g;
  }
}

// ---------------------------------------------------------------------------
// d2: out[b][o][n] = sum_c g[b][n][c] * W2[o][c]. (unchanged)
// ---------------------------------------------------------------------------
__global__ __launch_bounds__(256) void d2_kernel(const float* __restrict__ gbuf,
                                                 const float* __restrict__ W2,
                                                 float* __restrict__ out) {
  __shared__ float4 w2s[OO * 32];  // addr4 = o*32 + (c4 ^ (o&7))
  const int tid = threadIdx.x;
  const int b = blockIdx.y;
  const int n0 = blockIdx.x * 32;
  const float4* w2v = (const float4*)W2;
  for (int t = tid; t < OO * 32; t += 256) {
    int o = t >> 5, c4 = t & 31;
    w2s[o * 32 + (c4 ^ (o & 7))] = w2v[t];
  }
  __syncthreads();
  const int og = tid & 7;
  const int ni = tid >> 3;
  const int n = n0 + ni;
  const float4* gp = (const float4*)(gbuf + ((size_t)b * NN + n) * DD);
  float acc[16];
  #pragma unroll
  for (int j = 0; j < 16; ++j) acc[j] = 0.0f;
  for (int c4 = 0; c4 < 32; ++c4) {
    float4 g4 = gp[c4];
    #pragma unroll
    for (int j = 0; j < 16; ++j) {
      const int o = j * 8 + og;
      float4 w4 = w2s[o * 32 + (c4 ^ og)];
      acc[j] += g4.x * w4.x + g4.y * w4.y + g4.z * w4.z + g4.w * w4.w;
    }
  }
  float* outb = out + (size_t)b * OO * NN;
  #pragma unroll
  for (int j = 0; j < 16; ++j) {
    outb[(size_t)(j * 8 + og) * NN + n] = acc[j];
  }
}

// ---------------------------------------------------------------------------
// ws layout (bytes):
//   xt   @ 0          : 2,097,152 f32 =  8,388,608 B   (live: prep->d1)
//   xx   @ 8,388,608  :    32,768 f32 =    131,072 B   (live: prep->knn)
//   xs   @ 8,519,680  : 6,291,456 u16 = 12,582,912 B   (live: prep->knn)
//   gbuf @ 8,519,680  : 4,194,304 f32 = 16,777,216 B   (reuses xs after knn)
//   fidx @ 25,296,896 :   655,360 i32 =  2,621,440 B   (live: knn->d1)
// total: 27,918,336 B (~26.6 MB; previous accepted layout was 30.6 MB)
// ---------------------------------------------------------------------------
extern "C" void kernel_launch(void* const* d_in, const int* in_sizes, int n_in,
                              void* d_out, int out_size, void* d_ws, size_t ws_size,
                              hipStream_t stream) {
  const float* x  = (const float*)d_in[0];
  const float* W1 = (const float*)d_in[1];
  const float* W2 = (const float*)d_in[2];
  float* out = (float*)d_out;
  char* ws = (char*)d_ws;
  float* xt = (float*)(ws);
  float* xx = (float*)(ws + 8388608);
  unsigned short* xs = (unsigned short*)(ws + 8519680);
  float* gbuf = (float*)(ws + 8519680);
  int* fidx = (int*)(ws + 25296896);

  prep_kernel<<<dim3(NN / 128, BB), 128, 0, stream>>>(x, xt, xx, xs);
  knn_kernel<<<dim3(NN / 64, BB), 256, 0, stream>>>(xs, xx, fidx);
  d1_kernel<<<dim3(NN / 32, BB), 256, 0, stream>>>(xt, W1, fidx, gbuf);
  d2_kernel<<<dim3(NN / 32, BB), 256, 0, stream>>>(gbuf, W2, out);
}

// Round 3
// 805.038 us; speedup vs baseline: 1.6924x; 1.6924x over previous
//
#include <hip/hip_runtime.h>
#include <math.h>

#define BB 4
#define CC 64
#define NN 8192
#define OO 128
#define KK 20
#define DD 128            // 2*CC
#define BUFSZ 25          // knn per-lane append buffer

typedef short bf16x8 __attribute__((ext_vector_type(8)));   // 8 bf16 (4 VGPR)
typedef float f32x4 __attribute__((ext_vector_type(4)));
typedef unsigned short u16x8 __attribute__((ext_vector_type(8)));
typedef unsigned long long u64;

typedef __attribute__((address_space(1))) const void gvoid;
typedef __attribute__((address_space(3))) void lvoid;

// orderable-key packing: (float value, candidate idx) -> u64, so that
// u64-descending == (value desc, idx asc). Matches jax.lax.top_k tie-breaking.
__device__ __forceinline__ u64 packkey(float v, int idx) {
  unsigned u = __float_as_uint(v);
  unsigned o = ((int)u < 0) ? ~u : (u | 0x80000000u);
  return (((u64)o) << 32) | (unsigned)(~idx);
}
__device__ __forceinline__ float keyval(u64 k) {
  unsigned o = (unsigned)(k >> 32);
  unsigned u = (o & 0x80000000u) ? (o ^ 0x80000000u) : ~o;
  return __uint_as_float(u);
}
#define INITKEY (((u64)0x007FFFFFu) << 32)   // packkey(-inf, 0xFFFFFFFF)

__device__ __forceinline__ unsigned short bf_rne(float f) {
  unsigned u = __float_as_uint(f);
  u += 0x7FFFu + ((u >> 16) & 1u);
  return (unsigned short)(u >> 16);
}
__device__ __forceinline__ float bf_f(unsigned short h) {
  return __uint_as_float(((unsigned)h) << 16);
}

// ---------------------------------------------------------------------------
// prep: xx[b][n] and xs[b][n][192] = 3-way bf16 split [h(64)|m(64)|l(64)],
// PRE-SWIZZLED: 16B-group at logical byte o lands at o ^ ((n&7)<<4).
// (xt dropped: no consumer remains after the d1 MFMA rewrite.)
// ---------------------------------------------------------------------------
__global__ __launch_bounds__(128) void prep_kernel(const float* __restrict__ x,
                                                   float* __restrict__ xx,
                                                   unsigned short* __restrict__ xs) {
  const int tid = threadIdx.x;
  const int b = blockIdx.y;
  const int n0 = blockIdx.x * 128;
  const float* xb = x + (size_t)b * CC * NN;
  float xv[CC];
  float acc = 0.0f;
  #pragma unroll
  for (int c = 0; c < CC; ++c) {
    float v = xb[(size_t)c * NN + n0 + tid];   // coalesced over tid
    acc += v * v;
    xv[c] = v;
  }
  xx[b * NN + n0 + tid] = acc;

  const int n = n0 + tid;
  char* xsrow = ((char*)xs) + ((size_t)b * NN + n) * 384;
  const int swn = (n & 7) << 4;
  #pragma unroll
  for (int gr = 0; gr < 8; ++gr) {
    u16x8 h8, m8, l8;
    #pragma unroll
    for (int e = 0; e < 8; ++e) {
      float v = xv[gr * 8 + e];
      unsigned short h = bf_rne(v);
      float r = v - bf_f(h);
      unsigned short m = bf_rne(r);
      r -= bf_f(m);
      unsigned short l = bf_rne(r);
      h8[e] = (unsigned short)h; m8[e] = m; l8[e] = l;
    }
    *(u16x8*)(xsrow + (((gr * 16) + 0) ^ swn)) = h8;
    *(u16x8*)(xsrow + (((gr * 16) + 128) ^ swn)) = m8;
    *(u16x8*)(xsrow + (((gr * 16) + 256) ^ swn)) = l8;
  }
}

// ---------------------------------------------------------------------------
// knn: MFMA distance matrix + per-lane buffered top-20. (verified round 2;
// unchanged)
// ---------------------------------------------------------------------------
__global__ __launch_bounds__(256, 2) void knn_kernel(
    const unsigned short* __restrict__ xs, const float* __restrict__ xx,
    int* __restrict__ fidx) {
  __shared__ unsigned short atile[64 * 192];   // 24576 B, swizzled rows
  __shared__ float cxx[64];
  __shared__ u64 abuf[4][64][BUFSZ];           // 51200 B  (total LDS 76032 B)

  const int tid = threadIdx.x;
  const int w = tid >> 6;
  const int lane = tid & 63;
  const int r = lane & 15;    // query col (B) / cand row (A) within subtile
  const int g = lane >> 4;    // k-group
  const int b = blockIdx.y;
  const int qbase = blockIdx.x * 64 + w * 16;
  const int q = qbase + r;
  const char* xsb = ((const char*)xs) + (size_t)b * NN * 384;

  bf16x8 bq[3][2];
  {
    const char* qrow = xsb + (size_t)q * 384;
    const int sw = (q & 7) << 4;
    #pragma unroll
    for (int s = 0; s < 3; ++s)
      #pragma unroll
      for (int c = 0; c < 2; ++c)
        bq[s][c] = *(const bf16x8*)(qrow + ((s * 128 + c * 64 + g * 16) ^ sw));
  }
  const float xxq = xx[b * NN + q];

  u64 tk[KK];
  #pragma unroll
  for (int j = 0; j < KK; ++j) tk[j] = INITKEY;
  float minv = -INFINITY;
  int cnt = 0;
  u64* mybuf = &abuf[w][lane][0];

  for (int t = 0; t < NN / 64; ++t) {
    {
      const char* src = xsb + (size_t)t * 64 * 384;
      #pragma unroll
      for (int it = 0; it < 6; ++it) {
        __builtin_amdgcn_global_load_lds(
            (gvoid*)(src + it * 4096 + tid * 16),
            (lvoid*)(((char*)atile) + it * 4096 + tid * 16), 16, 0, 0);
      }
      if (tid < 16) {
        __builtin_amdgcn_global_load_lds(
            (gvoid*)(xx + b * NN + t * 64 + tid * 4),
            (lvoid*)(cxx + tid * 4), 16, 0, 0);
      }
    }
    __syncthreads();

    #pragma unroll
    for (int ct = 0; ct < 4; ++ct) {
      const char* arow = ((const char*)atile) + (ct * 16 + r) * 384;
      const int sw = (r & 7) << 4;
      bf16x8 a6[6];
      #pragma unroll
      for (int c6 = 0; c6 < 6; ++c6)
        a6[c6] = *(const bf16x8*)(arow + ((c6 * 64 + g * 16) ^ sw));
      f32x4 acc = {0.f, 0.f, 0.f, 0.f};
      #pragma unroll
      for (int s = 2; s >= 0; --s)
        #pragma unroll
        for (int c6 = 0; c6 < 6; ++c6)
          acc = __builtin_amdgcn_mfma_f32_16x16x32_bf16(a6[c6], bq[s][c6 & 1],
                                                        acc, 0, 0, 0);
      #pragma unroll
      for (int j = 0; j < 4; ++j) {
        const int ml = ct * 16 + g * 4 + j;
        float pd = (-xxq - (-2.0f * acc[j])) - cxx[ml];
        if (pd > minv) { mybuf[cnt] = packkey(pd, t * 64 + ml); ++cnt; }
      }
    }
    __syncthreads();

    if (__any(cnt > BUFSZ - 16)) {
      int mxc = cnt;
      #pragma unroll
      for (int o = 32; o > 0; o >>= 1) {
        int v = __shfl_xor(mxc, o);
        mxc = mxc > v ? mxc : v;
      }
      for (int i = 0; i < mxc; ++i) {
        u64 k = (i < cnt) ? mybuf[i] : 0ULL;
        if (k > tk[KK - 1]) {
          #pragma unroll
          for (int jj = KK - 1; jj >= 1; --jj)
            tk[jj] = (k > tk[jj - 1]) ? tk[jj - 1] : ((k > tk[jj]) ? k : tk[jj]);
          tk[0] = (k > tk[0]) ? k : tk[0];
        }
      }
      cnt = 0;
      minv = keyval(tk[KK - 1]);
    }
  }

  {
    int mxc = cnt;
    #pragma unroll
    for (int o = 32; o > 0; o >>= 1) {
      int v = __shfl_xor(mxc, o);
      mxc = mxc > v ? mxc : v;
    }
    for (int i = 0; i < mxc; ++i) {
      u64 k = (i < cnt) ? mybuf[i] : 0ULL;
      if (k > tk[KK - 1]) {
        #pragma unroll
        for (int jj = KK - 1; jj >= 1; --jj)
          tk[jj] = (k > tk[jj - 1]) ? tk[jj - 1] : ((k > tk[jj]) ? k : tk[jj]);
        tk[0] = (k > tk[0]) ? k : tk[0];
      }
    }
  }

  u64* ml = &abuf[w][0][0];
  #pragma unroll
  for (int j = 0; j < KK; ++j) ml[lane * KK + j] = tk[j];
  __syncthreads();
  if (lane < 16) {
    int* fo = fidx + ((size_t)b * NN + qbase + lane) * KK;
    const u64* L0 = ml + (lane + 0) * KK;
    const u64* L1 = ml + (lane + 16) * KK;
    const u64* L2 = ml + (lane + 32) * KK;
    const u64* L3 = ml + (lane + 48) * KK;
    int p0 = 0, p1 = 0, p2 = 0, p3 = 0;
    u64 h0 = L0[0], h1 = L1[0], h2 = L2[0], h3 = L3[0];
    #pragma unroll
    for (int k = 0; k < KK; ++k) {
      u64 bv = h0; int bc = 0;
      if (h1 > bv) { bv = h1; bc = 1; }
      if (h2 > bv) { bv = h2; bc = 2; }
      if (h3 > bv) { bv = h3; bc = 3; }
      fo[k] = (int)(~(unsigned)bv);
      if (bc == 0)      { ++p0; h0 = (p0 < KK) ? L0[p0] : 0ULL; }
      else if (bc == 1) { ++p1; h1 = (p1 < KK) ? L1[p1] : 0ULL; }
      else if (bc == 2) { ++p2; h2 = (p2 < KK) ? L2[p2] : 0ULL; }
      else              { ++p3; h3 = (p3 < KK) ? L3[p3] : 0ULL; }
    }
  }
}

// ---------------------------------------------------------------------------
// w1prep: pre-pack W1a^T (= W1[d<64][c<64]) as 3-way bf16-split MFMA B-frags.
// Frag f = (dt*2+kc)*3 + s; lane l holds 8 elems: d = dt*16+(l&15),
// c = kc*32+(l>>4)*8+j. 24 frags x 1024 B = 24576 B. Runs after knn,
// aliased into the then-dead xx region.
// ---------------------------------------------------------------------------
__global__ __launch_bounds__(256) void w1prep_kernel(const float* __restrict__ W1,
                                                     unsigned short* __restrict__ w1p) {
  for (int e = threadIdx.x; e < 12288; e += 256) {
    const int f = e >> 9;
    const int rr = e & 511;
    const int l = rr >> 3;
    const int j = rr & 7;
    const int pair = f / 3, s = f % 3;
    const int dt = pair >> 1, kc = pair & 1;
    const int d = dt * 16 + (l & 15);
    const int c = kc * 32 + (l >> 4) * 8 + j;
    const float v = W1[d * DD + c];
    const unsigned short h = bf_rne(v);
    float r = v - bf_f(h);
    const unsigned short m = bf_rne(r);
    r -= bf_f(m);
    const unsigned short lo = bf_rne(r);
    w1p[(size_t)f * 512 + l * 8 + j] = (s == 0) ? h : ((s == 1) ? m : lo);
  }
}

#define MFMA16(A, B, C) __builtin_amdgcn_mfma_f32_16x16x32_bf16((A), (B), (C), 0, 0, 0)

// one h-GEMM cross term (sa = A split, sb = B split), all indices compile-time
template <int SA, int SB>
__device__ __forceinline__ void h_term(const bf16x8 (&a)[3][2][2],
                                       const bf16x8 (&w1f)[24],
                                       f32x4 (&acc)[4][2]) {
  #pragma unroll
  for (int dt = 0; dt < 4; ++dt)
    #pragma unroll
    for (int kc = 0; kc < 2; ++kc) {
      const bf16x8 bf = w1f[(dt * 2 + kc) * 3 + SB];
      acc[dt][0] = MFMA16(a[SA][kc][0], bf, acc[dt][0]);
      acc[dt][1] = MFMA16(a[SA][kc][1], bf, acc[dt][1]);
    }
}

// epilogue for d-tile DT: Y re-layout via identity-B MFMA, masked softmax
// over k (shfl_xor across the 4 lane-groups), returns T[d] = sum_k y_k[d]*gate
template <int DT>
__device__ __forceinline__ float d1_epi(const bf16x8 (&a)[3][2][2],
                                        bf16x8 id0, bf16x8 id1,
                                        const f32x4 (&acc)[4][2], int g) {
  constexpr int KC = DT >> 1;
  const bf16x8 idp = (DT & 1) ? id1 : id0;
  f32x4 yf0 = {0.f, 0.f, 0.f, 0.f}, yf1 = {0.f, 0.f, 0.f, 0.f};
  yf0 = MFMA16(a[1][KC][0], idp, yf0);   // m split first (smaller)
  yf0 = MFMA16(a[0][KC][0], idp, yf0);
  yf1 = MFMA16(a[1][KC][1], idp, yf1);
  yf1 = MFMA16(a[0][KC][1], idp, yf1);
  const f32x4 h0 = acc[DT][0], h1 = acc[DT][1];
  float mx = fmaxf(fmaxf(h0[0], h0[1]), fmaxf(h0[2], h0[3]));
  mx = fmaxf(mx, fmaxf(fmaxf(h1[0], h1[1]), fmaxf(h1[2], h1[3])));  // dups harmless
  mx = fmaxf(mx, __shfl_xor(mx, 16));
  mx = fmaxf(mx, __shfl_xor(mx, 32));
  float sl = 0.f, tl = 0.f;
  #pragma unroll
  for (int j = 0; j < 4; ++j) {
    const float e = __expf(h0[j] - mx);
    sl += e; tl += yf0[j] * e;
  }
  if (g == 0) {   // tile1 rows k=16..19 counted exactly once (dup groups masked)
    #pragma unroll
    for (int j = 0; j < 4; ++j) {
      const float e = __expf(h1[j] - mx);
      sl += e; tl += yf1[j] * e;
    }
  }
  sl += __shfl_xor(sl, 16); sl += __shfl_xor(sl, 32);
  tl += __shfl_xor(tl, 16); tl += __shfl_xor(tl, 32);
  return tl / sl;
}

// ---------------------------------------------------------------------------
// d1 (MFMA rewrite). Exact algebra used:
//   td = z.(W1b-W1a) is k-constant -> cancels in softmax(axis=k): DROPPED.
//   sum_k gate[k][d] = 1 -> g[d>=64] = z[d-64] (no softmax for top half),
//   g[d<64] = (sum_k y_k[d]*gate[k][d]) - z[d]; gate needs h for d<64 only.
// One wave per n, no LDS, no barriers. A-frags gathered from xs (same
// verified layout/swizzle as knn's bq loads). B = pre-packed W1a^T splits.
// h: 6 cross terms x 4 dt x 2 kc x 2 mt = 96 MFMA; Y re-layout: 16 MFMA.
// ---------------------------------------------------------------------------
__global__ __launch_bounds__(256, 2) void d1_kernel(
    const unsigned short* __restrict__ xs, const int* __restrict__ fidx,
    const unsigned short* __restrict__ w1p, float* __restrict__ gbuf) {
  const int tid = threadIdx.x;
  const int w = tid >> 6;
  const int lane = tid & 63;
  const int r = lane & 15;
  const int g = lane >> 4;
  const int b = blockIdx.y;
  const char* xsb = ((const char*)xs) + (size_t)b * NN * 384;

  // hoisted n-invariant B-frags (96 VGPR)
  bf16x8 w1f[24];
  #pragma unroll
  for (int f = 0; f < 24; ++f)
    w1f[f] = *(const bf16x8*)(((const char*)w1p) + f * 1024 + lane * 16);

  // identity B-frags: select cols [p*16, p*16+16) of the K=32 chunk
  bf16x8 id0, id1;
  #pragma unroll
  for (int j = 0; j < 8; ++j) {
    id0[j] = (g == (r >> 3) && j == (r & 7)) ? (short)0x3F80 : (short)0;
    id1[j] = (g == 2 + (r >> 3) && j == (r & 7)) ? (short)0x3F80 : (short)0;
  }

  for (int i = 0; i < 4; ++i) {
    const int n = blockIdx.x * 16 + w * 4 + i;
    const size_t ng = (size_t)b * NN + n;
    const int* kp = fidx + ng * KK;
    const int row0 = kp[r];                 // tile0 row r -> neighbor r
    const int row1 = kp[16 + (r & 3)];      // tile1 row r -> neighbor 16+(r&3)
    const char* rp0 = xsb + (size_t)row0 * 384;
    const char* rp1 = xsb + (size_t)row1 * 384;
    const int sw0 = (row0 & 7) << 4, sw1 = (row1 & 7) << 4;

    bf16x8 a[3][2][2];
    #pragma unroll
    for (int s = 0; s < 3; ++s)
      #pragma unroll
      for (int kc = 0; kc < 2; ++kc) {
        const int off = s * 128 + kc * 64 + g * 16;
        a[s][kc][0] = *(const bf16x8*)(rp0 + (off ^ sw0));
        a[s][kc][1] = *(const bf16x8*)(rp1 + (off ^ sw1));
      }

    // z[c=lane] reconstructed to ~2^-27
    const char* zrow = xsb + (size_t)n * 384;
    const int swn = (n & 7) << 4;
    float zl;
    {
      const unsigned short zh = *(const unsigned short*)(zrow + ((2 * lane) ^ swn));
      const unsigned short zm = *(const unsigned short*)(zrow + ((128 + 2 * lane) ^ swn));
      const unsigned short zo = *(const unsigned short*)(zrow + ((256 + 2 * lane) ^ swn));
      zl = bf_f(zh) + bf_f(zm) + bf_f(zo);
    }

    f32x4 acc[4][2];
    #pragma unroll
    for (int dt = 0; dt < 4; ++dt) {
      acc[dt][0] = (f32x4){0.f, 0.f, 0.f, 0.f};
      acc[dt][1] = (f32x4){0.f, 0.f, 0.f, 0.f};
    }
    // smallest cross terms first
    h_term<2, 0>(a, w1f, acc);
    h_term<0, 2>(a, w1f, acc);
    h_term<1, 1>(a, w1f, acc);
    h_term<1, 0>(a, w1f, acc);
    h_term<0, 1>(a, w1f, acc);
    h_term<0, 0>(a, w1f, acc);

    const float t0 = d1_epi<0>(a, id0, id1, acc, g);
    const float t1 = d1_epi<1>(a, id0, id1, acc, g);
    const float t2 = d1_epi<2>(a, id0, id1, acc, g);
    const float t3 = d1_epi<3>(a, id0, id1, acc, g);

    float* go = gbuf + ng * DD;
    go[64 + lane] = zl;                     // g[d>=64] = z  (sum gate == 1)
    const float z0 = __shfl(zl, r);
    const float z1 = __shfl(zl, 16 + r);
    const float z2 = __shfl(zl, 32 + r);
    const float z3 = __shfl(zl, 48 + r);
    if (lane < 16) {
      go[r]      = t0 - z0;
      go[16 + r] = t1 - z1;
      go[32 + r] = t2 - z2;
      go[48 + r] = t3 - z3;
    }
  }
}

// ---------------------------------------------------------------------------
// d2: out[b][o][n] = sum_c g[b][n][c] * W2[o][c]. (unchanged)
// ---------------------------------------------------------------------------
__global__ __launch_bounds__(256) void d2_kernel(const float* __restrict__ gbuf,
                                                 const float* __restrict__ W2,
                                                 float* __restrict__ out) {
  __shared__ float4 w2s[OO * 32];  // addr4 = o*32 + (c4 ^ (o&7))
  const int tid = threadIdx.x;
  const int b = blockIdx.y;
  const int n0 = blockIdx.x * 32;
  const float4* w2v = (const float4*)W2;
  for (int t = tid; t < OO * 32; t += 256) {
    int o = t >> 5, c4 = t & 31;
    w2s[o * 32 + (c4 ^ (o & 7))] = w2v[t];
  }
  __syncthreads();
  const int og = tid & 7;
  const int ni = tid >> 3;
  const int n = n0 + ni;
  const float4* gp = (const float4*)(gbuf + ((size_t)b * NN + n) * DD);
  float acc[16];
  #pragma unroll
  for (int j = 0; j < 16; ++j) acc[j] = 0.0f;
  for (int c4 = 0; c4 < 32; ++c4) {
    float4 g4 = gp[c4];
    #pragma unroll
    for (int j = 0; j < 16; ++j) {
      const int o = j * 8 + og;
      float4 w4 = w2s[o * 32 + (c4 ^ og)];
      acc[j] += g4.x * w4.x + g4.y * w4.y + g4.z * w4.z + g4.w * w4.w;
    }
  }
  float* outb = out + (size_t)b * OO * NN;
  #pragma unroll
  for (int j = 0; j < 16; ++j) {
    outb[(size_t)(j * 8 + og) * NN + n] = acc[j];
  }
}

// ---------------------------------------------------------------------------
// ws layout (bytes):
//   xs   @ 0          : 6,291,456 u16 = 12,582,912 B  (live: prep->knn,d1)
//   xx   @ 12,582,912 :    32,768 f32 =    131,072 B  (live: prep->knn)
//   w1p  @ 12,582,912 :    12,288 u16 =     24,576 B  (aliases dead xx; w1prep->d1)
//   fidx @ 12,713,984 :   655,360 i32 =  2,621,440 B  (live: knn->d1)
//   gbuf @ 15,335,424 : 4,194,304 f32 = 16,777,216 B  (live: d1->d2)
// total: 32,112,640 B (== previously-accepted session total)
// ---------------------------------------------------------------------------
extern "C" void kernel_launch(void* const* d_in, const int* in_sizes, int n_in,
                              void* d_out, int out_size, void* d_ws, size_t ws_size,
                              hipStream_t stream) {
  const float* x  = (const float*)d_in[0];
  const float* W1 = (const float*)d_in[1];
  const float* W2 = (const float*)d_in[2];
  float* out = (float*)d_out;
  char* ws = (char*)d_ws;
  unsigned short* xs = (unsigned short*)(ws);
  float* xx = (float*)(ws + 12582912);
  unsigned short* w1p = (unsigned short*)(ws + 12582912);
  int* fidx = (int*)(ws + 12713984);
  float* gbuf = (float*)(ws + 15335424);

  prep_kernel<<<dim3(NN / 128, BB), 128, 0, stream>>>(x, xx, xs);
  knn_kernel<<<dim3(NN / 64, BB), 256, 0, stream>>>(xs, xx, fidx);
  w1prep_kernel<<<dim3(1), 256, 0, stream>>>(W1, w1p);   // after knn: xx dead
  d1_kernel<<<dim3(NN / 16, BB), 256, 0, stream>>>(xs, fidx, w1p, gbuf);
  d2_kernel<<<dim3(NN / 32, BB), 256, 0, stream>>>(gbuf, W2, out);
}

// Round 4
// 791.219 us; speedup vs baseline: 1.7219x; 1.0175x over previous
//
#include <hip/hip_runtime.h>
#include <math.h>

#define BB 4
#define CC 64
#define NN 8192
#define OO 128
#define KK 20
#define DD 128            // 2*CC
#define BUFSZ 15          // per-lane append buffer (checked twice per tile: cnt<=7 -> +8 max)

typedef short bf16x8 __attribute__((ext_vector_type(8)));   // 8 bf16 (4 VGPR)
typedef float f32x4 __attribute__((ext_vector_type(4)));
typedef unsigned short u16x8 __attribute__((ext_vector_type(8)));
typedef unsigned long long u64;

typedef __attribute__((address_space(1))) const void gvoid;
typedef __attribute__((address_space(3))) void lvoid;

// orderable-key packing: (float value, candidate idx) -> u64, so that
// u64-descending == (value desc, idx asc). Matches jax.lax.top_k tie-breaking.
__device__ __forceinline__ u64 packkey(float v, int idx) {
  unsigned u = __float_as_uint(v);
  unsigned o = ((int)u < 0) ? ~u : (u | 0x80000000u);
  return (((u64)o) << 32) | (unsigned)(~idx);
}
__device__ __forceinline__ float keyval(u64 k) {
  unsigned o = (unsigned)(k >> 32);
  unsigned u = (o & 0x80000000u) ? (o ^ 0x80000000u) : ~o;
  return __uint_as_float(u);
}
#define INITKEY (((u64)0x007FFFFFu) << 32)   // packkey(-inf, 0xFFFFFFFF)

__device__ __forceinline__ unsigned short bf_rne(float f) {
  unsigned u = __float_as_uint(f);
  u += 0x7FFFu + ((u >> 16) & 1u);
  return (unsigned short)(u >> 16);
}
__device__ __forceinline__ float bf_f(unsigned short h) {
  return __uint_as_float(((unsigned)h) << 16);
}

// ---------------------------------------------------------------------------
// prep: xx[b][n] and xs[b][n][192] = 3-way bf16 split [h(64)|m(64)|l(64)],
// PRE-SWIZZLED: 16B-group at logical byte o lands at o ^ ((n&7)<<4).
// (unchanged from round-3 pass)
// ---------------------------------------------------------------------------
__global__ __launch_bounds__(128) void prep_kernel(const float* __restrict__ x,
                                                   float* __restrict__ xx,
                                                   unsigned short* __restrict__ xs) {
  const int tid = threadIdx.x;
  const int b = blockIdx.y;
  const int n0 = blockIdx.x * 128;
  const float* xb = x + (size_t)b * CC * NN;
  float xv[CC];
  float acc = 0.0f;
  #pragma unroll
  for (int c = 0; c < CC; ++c) {
    float v = xb[(size_t)c * NN + n0 + tid];   // coalesced over tid
    acc += v * v;
    xv[c] = v;
  }
  xx[b * NN + n0 + tid] = acc;

  const int n = n0 + tid;
  char* xsrow = ((char*)xs) + ((size_t)b * NN + n) * 384;
  const int swn = (n & 7) << 4;
  #pragma unroll
  for (int gr = 0; gr < 8; ++gr) {
    u16x8 h8, m8, l8;
    #pragma unroll
    for (int e = 0; e < 8; ++e) {
      float v = xv[gr * 8 + e];
      unsigned short h = bf_rne(v);
      float r = v - bf_f(h);
      unsigned short m = bf_rne(r);
      r -= bf_f(m);
      unsigned short l = bf_rne(r);
      h8[e] = (unsigned short)h; m8[e] = m; l8[e] = l;
    }
    *(u16x8*)(xsrow + (((gr * 16) + 0) ^ swn)) = h8;
    *(u16x8*)(xsrow + (((gr * 16) + 128) ^ swn)) = m8;
    *(u16x8*)(xsrow + (((gr * 16) + 256) ^ swn)) = l8;
  }
}

// ---------------------------------------------------------------------------
// knn: MFMA distance matrix + per-lane buffered top-20.
// ROUND-4 CHANGE: double-buffered candidate staging (issue tile t+1's
// global_load_lds BEFORE computing tile t -> the compiler's vmcnt(0) drain
// at the single per-tile barrier lands after ~2800 cyc of compute; staging
// latency fully hidden; barriers/tile 2 -> 1). s_setprio(1) around MFMA
// chains (2 blocks/CU -> cross-block phase diversity). BUFSZ 25 -> 15 to fit
// 2 blocks/CU (80,384 B LDS); rebuild threshold checked twice per tile
// (invariant: cnt<=7 at each check, +8 appends max per subtile pair -> max
// write index 14). Epilogue merge scratch moved into the then-dead atile.
// Selection math bit-identical to the round-3 pass.
// ---------------------------------------------------------------------------
__global__ __launch_bounds__(256, 2) void knn_kernel(
    const unsigned short* __restrict__ xs, const float* __restrict__ xx,
    int* __restrict__ fidx) {
  __shared__ __attribute__((aligned(16))) unsigned short atile[2][64 * 192]; // 49152 B
  __shared__ float cxx[2][64];                                               //   512 B
  __shared__ u64 abuf[4][64][BUFSZ];                                         // 30720 B
                                                                             // total 80384 B
  const int tid = threadIdx.x;
  const int w = tid >> 6;
  const int lane = tid & 63;
  const int r = lane & 15;    // query col (B) / cand row (A) within subtile
  const int g = lane >> 4;    // k-group
  const int b = blockIdx.y;
  const int qbase = blockIdx.x * 64 + w * 16;
  const int q = qbase + r;
  const char* xsb = ((const char*)xs) + (size_t)b * NN * 384;

  // query B-frags: bq[split][k-chunk]; lane holds k = (lane>>4)*8+[0..8) of 32
  bf16x8 bq[3][2];
  {
    const char* qrow = xsb + (size_t)q * 384;
    const int sw = (q & 7) << 4;
    #pragma unroll
    for (int s = 0; s < 3; ++s)
      #pragma unroll
      for (int c = 0; c < 2; ++c)
        bq[s][c] = *(const bf16x8*)(qrow + ((s * 128 + c * 64 + g * 16) ^ sw));
  }
  const float xxq = xx[b * NN + q];

  u64 tk[KK];
  #pragma unroll
  for (int j = 0; j < KK; ++j) tk[j] = INITKEY;
  float minv = -INFINITY;
  int cnt = 0;
  u64* mybuf = &abuf[w][lane][0];

  // stage tile t into buffer p
  auto stage = [&](int t, int p) {
    const char* src = xsb + (size_t)t * 64 * 384;
    char* dst = (char*)atile[p];
    #pragma unroll
    for (int it = 0; it < 6; ++it) {
      __builtin_amdgcn_global_load_lds(
          (gvoid*)(src + it * 4096 + tid * 16),
          (lvoid*)(dst + it * 4096 + tid * 16), 16, 0, 0);
    }
    if (tid < 16) {
      __builtin_amdgcn_global_load_lds(
          (gvoid*)(xx + b * NN + t * 64 + tid * 4),
          (lvoid*)(cxx[p] + tid * 4), 16, 0, 0);
    }
  };

  // fold buffered candidates into the register-sorted top-20, tighten minv
  auto rebuild = [&]() {
    int mxc = cnt;
    #pragma unroll
    for (int o = 32; o > 0; o >>= 1) {
      int v = __shfl_xor(mxc, o);
      mxc = mxc > v ? mxc : v;
    }
    for (int i = 0; i < mxc; ++i) {
      u64 k = (i < cnt) ? mybuf[i] : 0ULL;
      if (k > tk[KK - 1]) {
        #pragma unroll
        for (int jj = KK - 1; jj >= 1; --jj)
          tk[jj] = (k > tk[jj - 1]) ? tk[jj - 1] : ((k > tk[jj]) ? k : tk[jj]);
        tk[0] = (k > tk[0]) ? k : tk[0];
      }
    }
    cnt = 0;
    minv = keyval(tk[KK - 1]);
  };

  stage(0, 0);
  __syncthreads();

  for (int t = 0; t < NN / 64; ++t) {
    const int p = t & 1;
    if (t < NN / 64 - 1) stage(t + 1, p ^ 1);   // in flight during compute

    #pragma unroll
    for (int half = 0; half < 2; ++half) {
      #pragma unroll
      for (int cth = 0; cth < 2; ++cth) {
        const int ct = half * 2 + cth;
        const char* arow = ((const char*)atile[p]) + (ct * 16 + r) * 384;
        const int sw = (r & 7) << 4;
        bf16x8 a6[6];
        #pragma unroll
        for (int c6 = 0; c6 < 6; ++c6)
          a6[c6] = *(const bf16x8*)(arow + ((c6 * 64 + g * 16) ^ sw));
        f32x4 acc = {0.f, 0.f, 0.f, 0.f};
        __builtin_amdgcn_s_setprio(1);
        #pragma unroll
        for (int s = 2; s >= 0; --s)   // b-split l,m first: small terms first
          #pragma unroll
          for (int c6 = 0; c6 < 6; ++c6)
            acc = __builtin_amdgcn_mfma_f32_16x16x32_bf16(a6[c6], bq[s][c6 & 1],
                                                          acc, 0, 0, 0);
        __builtin_amdgcn_s_setprio(0);
        #pragma unroll
        for (int j = 0; j < 4; ++j) {
          const int ml = ct * 16 + g * 4 + j;
          float pd = (-xxq - (-2.0f * acc[j])) - cxx[p][ml];
          if (pd > minv) { mybuf[cnt] = packkey(pd, t * 64 + ml); ++cnt; }
        }
      }
      // invariant: cnt<=7 entering a subtile pair; <=8 appends per pair
      if (__any(cnt > 7)) rebuild();
    }
    __syncthreads();   // buf[p^1] now resident; buf[p] free for next stage
  }

  rebuild();   // flush remaining buffered candidates

  // --- epilogue: 4-way merge of the per-lane class lists -> fidx ---
  // scratch: atile is dead now (all waves passed the final barrier)
  u64* ml = ((u64*)&atile[0][0]) + (size_t)w * 64 * KK;   // 10240 B per wave
  #pragma unroll
  for (int j = 0; j < KK; ++j) ml[lane * KK + j] = tk[j];
  __syncthreads();
  if (lane < 16) {
    int* fo = fidx + ((size_t)b * NN + qbase + lane) * KK;
    const u64* L0 = ml + (lane + 0) * KK;
    const u64* L1 = ml + (lane + 16) * KK;
    const u64* L2 = ml + (lane + 32) * KK;
    const u64* L3 = ml + (lane + 48) * KK;
    int p0 = 0, p1 = 0, p2 = 0, p3 = 0;
    u64 h0 = L0[0], h1 = L1[0], h2 = L2[0], h3 = L3[0];
    #pragma unroll
    for (int k = 0; k < KK; ++k) {
      u64 bv = h0; int bc = 0;
      if (h1 > bv) { bv = h1; bc = 1; }
      if (h2 > bv) { bv = h2; bc = 2; }
      if (h3 > bv) { bv = h3; bc = 3; }
      fo[k] = (int)(~(unsigned)bv);
      if (bc == 0)      { ++p0; h0 = (p0 < KK) ? L0[p0] : 0ULL; }
      else if (bc == 1) { ++p1; h1 = (p1 < KK) ? L1[p1] : 0ULL; }
      else if (bc == 2) { ++p2; h2 = (p2 < KK) ? L2[p2] : 0ULL; }
      else              { ++p3; h3 = (p3 < KK) ? L3[p3] : 0ULL; }
    }
  }
}

// ---------------------------------------------------------------------------
// w1prep: pre-pack W1a^T as 3-way bf16-split MFMA B-frags. (unchanged)
// ---------------------------------------------------------------------------
__global__ __launch_bounds__(256) void w1prep_kernel(const float* __restrict__ W1,
                                                     unsigned short* __restrict__ w1p) {
  for (int e = threadIdx.x; e < 12288; e += 256) {
    const int f = e >> 9;
    const int rr = e & 511;
    const int l = rr >> 3;
    const int j = rr & 7;
    const int pair = f / 3, s = f % 3;
    const int dt = pair >> 1, kc = pair & 1;
    const int d = dt * 16 + (l & 15);
    const int c = kc * 32 + (l >> 4) * 8 + j;
    const float v = W1[d * DD + c];
    const unsigned short h = bf_rne(v);
    float r = v - bf_f(h);
    const unsigned short m = bf_rne(r);
    r -= bf_f(m);
    const unsigned short lo = bf_rne(r);
    w1p[(size_t)f * 512 + l * 8 + j] = (s == 0) ? h : ((s == 1) ? m : lo);
  }
}

#define MFMA16(A, B, C) __builtin_amdgcn_mfma_f32_16x16x32_bf16((A), (B), (C), 0, 0, 0)

// one h-GEMM cross term (SA = A split, SB = B split), indices compile-time
template <int SA, int SB>
__device__ __forceinline__ void h_term(const bf16x8 (&a)[3][2][2],
                                       const bf16x8 (&w1f)[24],
                                       f32x4 (&acc)[4][2]) {
  #pragma unroll
  for (int dt = 0; dt < 4; ++dt)
    #pragma unroll
    for (int kc = 0; kc < 2; ++kc) {
      const bf16x8 bf = w1f[(dt * 2 + kc) * 3 + SB];
      acc[dt][0] = MFMA16(a[SA][kc][0], bf, acc[dt][0]);
      acc[dt][1] = MFMA16(a[SA][kc][1], bf, acc[dt][1]);
    }
}

// epilogue for d-tile DT: Y re-layout via identity-B MFMA, masked softmax
// over k (shfl_xor across the 4 lane-groups), returns T[d] = sum_k y_k[d]*gate
template <int DT>
__device__ __forceinline__ float d1_epi(const bf16x8 (&a)[3][2][2],
                                        bf16x8 id0, bf16x8 id1,
                                        const f32x4 (&acc)[4][2], int g) {
  constexpr int KC = DT >> 1;
  const bf16x8 idp = (DT & 1) ? id1 : id0;
  f32x4 yf0 = {0.f, 0.f, 0.f, 0.f}, yf1 = {0.f, 0.f, 0.f, 0.f};
  yf0 = MFMA16(a[1][KC][0], idp, yf0);   // m split first (smaller)
  yf0 = MFMA16(a[0][KC][0], idp, yf0);
  yf1 = MFMA16(a[1][KC][1], idp, yf1);
  yf1 = MFMA16(a[0][KC][1], idp, yf1);
  const f32x4 h0 = acc[DT][0], h1 = acc[DT][1];
  float mx = fmaxf(fmaxf(h0[0], h0[1]), fmaxf(h0[2], h0[3]));
  mx = fmaxf(mx, fmaxf(fmaxf(h1[0], h1[1]), fmaxf(h1[2], h1[3])));  // dups harmless
  mx = fmaxf(mx, __shfl_xor(mx, 16));
  mx = fmaxf(mx, __shfl_xor(mx, 32));
  float sl = 0.f, tl = 0.f;
  #pragma unroll
  for (int j = 0; j < 4; ++j) {
    const float e = __expf(h0[j] - mx);
    sl += e; tl += yf0[j] * e;
  }
  if (g == 0) {   // tile1 rows k=16..19 counted exactly once (dup groups masked)
    #pragma unroll
    for (int j = 0; j < 4; ++j) {
      const float e = __expf(h1[j] - mx);
      sl += e; tl += yf1[j] * e;
    }
  }
  sl += __shfl_xor(sl, 16); sl += __shfl_xor(sl, 32);
  tl += __shfl_xor(tl, 16); tl += __shfl_xor(tl, 32);
  return tl / sl;
}

// ---------------------------------------------------------------------------
// d1 (MFMA rewrite; unchanged from round-3 pass).
//   td = z.(W1b-W1a) is k-constant -> cancels in softmax(axis=k): DROPPED.
//   sum_k gate[k][d] = 1 -> g[d>=64] = z[d-64]; g[d<64] = (sum_k y_k[d]*gate)
//   - z[d]. One wave per n, no LDS, no barriers.
// ---------------------------------------------------------------------------
__global__ __launch_bounds__(256, 2) void d1_kernel(
    const unsigned short* __restrict__ xs, const int* __restrict__ fidx,
    const unsigned short* __restrict__ w1p, float* __restrict__ gbuf) {
  const int tid = threadIdx.x;
  const int w = tid >> 6;
  const int lane = tid & 63;
  const int r = lane & 15;
  const int g = lane >> 4;
  const int b = blockIdx.y;
  const char* xsb = ((const char*)xs) + (size_t)b * NN * 384;

  // hoisted n-invariant B-frags (96 VGPR)
  bf16x8 w1f[24];
  #pragma unroll
  for (int f = 0; f < 24; ++f)
    w1f[f] = *(const bf16x8*)(((const char*)w1p) + f * 1024 + lane * 16);

  // identity B-frags: select cols [p*16, p*16+16) of the K=32 chunk
  bf16x8 id0, id1;
  #pragma unroll
  for (int j = 0; j < 8; ++j) {
    id0[j] = (g == (r >> 3) && j == (r & 7)) ? (short)0x3F80 : (short)0;
    id1[j] = (g == 2 + (r >> 3) && j == (r & 7)) ? (short)0x3F80 : (short)0;
  }

  for (int i = 0; i < 4; ++i) {
    const int n = blockIdx.x * 16 + w * 4 + i;
    const size_t ng = (size_t)b * NN + n;
    const int* kp = fidx + ng * KK;
    const int row0 = kp[r];                 // tile0 row r -> neighbor r
    const int row1 = kp[16 + (r & 3)];      // tile1 row r -> neighbor 16+(r&3)
    const char* rp0 = xsb + (size_t)row0 * 384;
    const char* rp1 = xsb + (size_t)row1 * 384;
    const int sw0 = (row0 & 7) << 4, sw1 = (row1 & 7) << 4;

    bf16x8 a[3][2][2];
    #pragma unroll
    for (int s = 0; s < 3; ++s)
      #pragma unroll
      for (int kc = 0; kc < 2; ++kc) {
        const int off = s * 128 + kc * 64 + g * 16;
        a[s][kc][0] = *(const bf16x8*)(rp0 + (off ^ sw0));
        a[s][kc][1] = *(const bf16x8*)(rp1 + (off ^ sw1));
      }

    // z[c=lane] reconstructed to ~2^-27
    const char* zrow = xsb + (size_t)n * 384;
    const int swn = (n & 7) << 4;
    float zl;
    {
      const unsigned short zh = *(const unsigned short*)(zrow + ((2 * lane) ^ swn));
      const unsigned short zm = *(const unsigned short*)(zrow + ((128 + 2 * lane) ^ swn));
      const unsigned short zo = *(const unsigned short*)(zrow + ((256 + 2 * lane) ^ swn));
      zl = bf_f(zh) + bf_f(zm) + bf_f(zo);
    }

    f32x4 acc[4][2];
    #pragma unroll
    for (int dt = 0; dt < 4; ++dt) {
      acc[dt][0] = (f32x4){0.f, 0.f, 0.f, 0.f};
      acc[dt][1] = (f32x4){0.f, 0.f, 0.f, 0.f};
    }
    // smallest cross terms first
    h_term<2, 0>(a, w1f, acc);
    h_term<0, 2>(a, w1f, acc);
    h_term<1, 1>(a, w1f, acc);
    h_term<1, 0>(a, w1f, acc);
    h_term<0, 1>(a, w1f, acc);
    h_term<0, 0>(a, w1f, acc);

    const float t0 = d1_epi<0>(a, id0, id1, acc, g);
    const float t1 = d1_epi<1>(a, id0, id1, acc, g);
    const float t2 = d1_epi<2>(a, id0, id1, acc, g);
    const float t3 = d1_epi<3>(a, id0, id1, acc, g);

    float* go = gbuf + ng * DD;
    go[64 + lane] = zl;                     // g[d>=64] = z  (sum gate == 1)
    const float z0 = __shfl(zl, r);
    const float z1 = __shfl(zl, 16 + r);
    const float z2 = __shfl(zl, 32 + r);
    const float z3 = __shfl(zl, 48 + r);
    if (lane < 16) {
      go[r]      = t0 - z0;
      go[16 + r] = t1 - z1;
      go[32 + r] = t2 - z2;
      go[48 + r] = t3 - z3;
    }
  }
}

// ---------------------------------------------------------------------------
// d2: out[b][o][n] = sum_c g[b][n][c] * W2[o][c]. (unchanged)
// ---------------------------------------------------------------------------
__global__ __launch_bounds__(256) void d2_kernel(const float* __restrict__ gbuf,
                                                 const float* __restrict__ W2,
                                                 float* __restrict__ out) {
  __shared__ float4 w2s[OO * 32];  // addr4 = o*32 + (c4 ^ (o&7))
  const int tid = threadIdx.x;
  const int b = blockIdx.y;
  const int n0 = blockIdx.x * 32;
  const float4* w2v = (const float4*)W2;
  for (int t = tid; t < OO * 32; t += 256) {
    int o = t >> 5, c4 = t & 31;
    w2s[o * 32 + (c4 ^ (o & 7))] = w2v[t];
  }
  __syncthreads();
  const int og = tid & 7;
  const int ni = tid >> 3;
  const int n = n0 + ni;
  const float4* gp = (const float4*)(gbuf + ((size_t)b * NN + n) * DD);
  float acc[16];
  #pragma unroll
  for (int j = 0; j < 16; ++j) acc[j] = 0.0f;
  for (int c4 = 0; c4 < 32; ++c4) {
    float4 g4 = gp[c4];
    #pragma unroll
    for (int j = 0; j < 16; ++j) {
      const int o = j * 8 + og;
      float4 w4 = w2s[o * 32 + (c4 ^ og)];
      acc[j] += g4.x * w4.x + g4.y * w4.y + g4.z * w4.z + g4.w * w4.w;
    }
  }
  float* outb = out + (size_t)b * OO * NN;
  #pragma unroll
  for (int j = 0; j < 16; ++j) {
    outb[(size_t)(j * 8 + og) * NN + n] = acc[j];
  }
}

// ---------------------------------------------------------------------------
// ws layout (bytes):
//   xs   @ 0          : 6,291,456 u16 = 12,582,912 B  (live: prep->knn,d1)
//   xx   @ 12,582,912 :    32,768 f32 =    131,072 B  (live: prep->knn)
//   w1p  @ 12,582,912 :    12,288 u16 =     24,576 B  (aliases dead xx; w1prep->d1)
//   fidx @ 12,713,984 :   655,360 i32 =  2,621,440 B  (live: knn->d1)
//   gbuf @ 15,335,424 : 4,194,304 f32 = 16,777,216 B  (live: d1->d2)
// total: 32,112,640 B
// ---------------------------------------------------------------------------
extern "C" void kernel_launch(void* const* d_in, const int* in_sizes, int n_in,
                              void* d_out, int out_size, void* d_ws, size_t ws_size,
                              hipStream_t stream) {
  const float* x  = (const float*)d_in[0];
  const float* W1 = (const float*)d_in[1];
  const float* W2 = (const float*)d_in[2];
  float* out = (float*)d_out;
  char* ws = (char*)d_ws;
  unsigned short* xs = (unsigned short*)(ws);
  float* xx = (float*)(ws + 12582912);
  unsigned short* w1p = (unsigned short*)(ws + 12582912);
  int* fidx = (int*)(ws + 12713984);
  float* gbuf = (float*)(ws + 15335424);

  prep_kernel<<<dim3(NN / 128, BB), 128, 0, stream>>>(x, xx, xs);
  knn_kernel<<<dim3(NN / 64, BB), 256, 0, stream>>>(xs, xx, fidx);
  w1prep_kernel<<<dim3(1), 256, 0, stream>>>(W1, w1p);   // after knn: xx dead
  d1_kernel<<<dim3(NN / 16, BB), 256, 0, stream>>>(xs, fidx, w1p, gbuf);
  d2_kernel<<<dim3(NN / 32, BB), 256, 0, stream>>>(gbuf, W2, out);
}